// Round 1
// baseline (8808.223 us; speedup 1.0000x reference)
//
#include <hip/hip_runtime.h>
#include <math.h>
#include <stdint.h>

#define NN 100000   // nodes
#define NE 3200000  // edges
#define NF 512      // feat
#define NH 256      // hidden
#define NC 40       // classes
#define NL 8        // layers

typedef __attribute__((ext_vector_type(8))) short short8;
typedef __attribute__((ext_vector_type(4))) float f32x4;

__device__ __forceinline__ unsigned short f2bf(float f) {
  union { float f; unsigned u; } v; v.f = f;
  return (unsigned short)((v.u + 0x7fffu + ((v.u >> 16) & 1u)) >> 16);
}
__device__ __forceinline__ float bf2f(unsigned short h) {
  union { unsigned u; float f; } v; v.u = ((unsigned)h) << 16;
  return v.f;
}

// ---------------- weight packing: W[K,256] f32 -> bf16 packed [K/32][256][32] ----------------
__global__ void pack_w(const float* __restrict__ W, unsigned short* __restrict__ out, int K) {
  int idx = blockIdx.x * 256 + threadIdx.x;  // grid covers K*256 exactly
  int k = idx >> 8, n = idx & 255;
  out[((size_t)(k >> 5) * NH + n) * 32 + (k & 31)] = f2bf(W[(size_t)k * NH + n]);
}

// dyn fold: Wd[l][k][n] = dyn_w[l][k][n] - dyn_w[l][k+256][n], packed per layer
__global__ void pack_dyn(const float* __restrict__ dynw, unsigned short* __restrict__ out) {
  int idx = blockIdx.x * 256 + threadIdx.x;  // NL*256*256
  int l = idx >> 16;
  int r = idx & 65535;
  int k = r >> 8, n = r & 255;
  float v = dynw[(size_t)l * NF * NH + (size_t)k * NH + n] -
            dynw[(size_t)l * NF * NH + (size_t)(k + NH) * NH + n];
  out[(size_t)l * 65536 + ((size_t)(k >> 5) * NH + n) * 32 + (k & 31)] = f2bf(v);
}

// ---------------- CSR build ----------------
__global__ void count_deg(const int* __restrict__ dst, int* __restrict__ deg) {
  int i = blockIdx.x * 256 + threadIdx.x;  // NE exact
  atomicAdd(&deg[dst[i]], 1);
}

__global__ void scan_deg(int* __restrict__ deg, int* __restrict__ rp) {
  __shared__ int sums[256];
  int t = threadIdx.x;
  const int CH = (NN + 255) / 256;  // 391
  int lo = t * CH, hi = lo + CH; if (hi > NN) hi = NN;
  int s = 0;
  for (int i = lo; i < hi; i++) s += deg[i];
  sums[t] = s; __syncthreads();
  for (int off = 1; off < 256; off <<= 1) {
    int v = (t >= off) ? sums[t - off] : 0;
    __syncthreads();
    sums[t] += v;
    __syncthreads();
  }
  int run = (t == 0) ? 0 : sums[t - 1];
  for (int i = lo; i < hi; i++) {
    int dv = deg[i];          // read before overwrite (deg aliases 'next')
    rp[i] = run; deg[i] = run;
    run += dv;
  }
  if (t == 255) rp[NN] = run;
}

__global__ void scatter_edges(const int* __restrict__ src, const int* __restrict__ dst,
                              const float* __restrict__ w, int* __restrict__ nxt,
                              int* __restrict__ cs, float* __restrict__ cw) {
  int i = blockIdx.x * 256 + threadIdx.x;  // NE exact
  int d = dst[i];
  int p = atomicAdd(&nxt[d], 1);
  cs[p] = src[i];
  cw[p] = w[i];
}

// ---------------- SpMM: support[:, :256] = bf16( adj @ h_bf16 ) ----------------
__global__ void spmm_kernel(const int* __restrict__ rp, const int* __restrict__ cs,
                            const float* __restrict__ cw,
                            const unsigned short* __restrict__ h16,
                            unsigned short* __restrict__ support) {
  int node = blockIdx.x;
  int f = threadIdx.x * 2;  // 128 threads, 2 feats each
  int beg = rp[node], end = rp[node + 1];
  float a0 = 0.f, a1 = 0.f;
  for (int e = beg; e < end; e++) {
    int s = cs[e];
    float w = cw[e];
    unsigned pv = *(const unsigned*)(h16 + (size_t)s * NH + f);
    a0 += w * bf2f((unsigned short)(pv & 0xffffu));
    a1 += w * bf2f((unsigned short)(pv >> 16));
  }
  unsigned o = (unsigned)f2bf(a0) | ((unsigned)f2bf(a1) << 16);
  *(unsigned*)(support + (size_t)node * NF + f) = o;
}

// ---------------- MFMA GEMM: C[M,256] = A[M,K] @ Bpack, fused epilogues ----------------
// mode 0 = FC:   v = relu(acc + bias);       write support[:,256:], h32, h16
// mode 1 = CONV: v = relu(theta*acc + (1-theta)*(0.9*hi + 0.1*h0) + h_prev); write h32, h16
// mode 2 = DYN:  v = relu(acc + bias) + axd * h0;  write d32, d16
template <bool AF32>
__global__ __launch_bounds__(256)
void gemm256(const void* __restrict__ Aptr, int lda, int K,
             const unsigned short* __restrict__ Bp,
             int mode, float theta, const float* __restrict__ bias,
             unsigned short* __restrict__ support,
             float* __restrict__ h32, unsigned short* __restrict__ h16,
             float* __restrict__ d32, unsigned short* __restrict__ d16,
             float axd) {
  int tid = threadIdx.x;
  int wave = tid >> 6, lane = tid & 63;
  int quad = lane >> 4, lrow = lane & 15;
  int bm = blockIdx.x * 64 + wave * 16;
  int arow = bm + lrow;
  if (arow >= NN) arow = NN - 1;

  f32x4 acc[16];
  f32x4 zero = {0.f, 0.f, 0.f, 0.f};
#pragma unroll
  for (int i = 0; i < 16; i++) acc[i] = zero;

  for (int k0 = 0; k0 < K; k0 += 32) {
    short8 afrag;
    if (AF32) {
      const float* A = (const float*)Aptr + (size_t)arow * lda + k0 + quad * 8;
      float4 x0 = *(const float4*)A;
      float4 x1 = *(const float4*)(A + 4);
      afrag[0] = (short)f2bf(x0.x); afrag[1] = (short)f2bf(x0.y);
      afrag[2] = (short)f2bf(x0.z); afrag[3] = (short)f2bf(x0.w);
      afrag[4] = (short)f2bf(x1.x); afrag[5] = (short)f2bf(x1.y);
      afrag[6] = (short)f2bf(x1.z); afrag[7] = (short)f2bf(x1.w);
    } else {
      const unsigned short* A = (const unsigned short*)Aptr + (size_t)arow * lda + k0 + quad * 8;
      afrag = *(const short8*)A;
    }
    const unsigned short* Bk = Bp + ((size_t)(k0 >> 5) * NH + lrow) * 32 + quad * 8;
#pragma unroll
    for (int nt = 0; nt < 16; nt++) {
      short8 bfrag = *(const short8*)(Bk + (size_t)nt * 16 * 32);
      acc[nt] = __builtin_amdgcn_mfma_f32_16x16x32_bf16(afrag, bfrag, acc[nt], 0, 0, 0);
    }
  }

#pragma unroll
  for (int nt = 0; nt < 16; nt++) {
    int col = nt * 16 + lrow;
#pragma unroll
    for (int r = 0; r < 4; r++) {
      int row = bm + quad * 4 + r;
      if (row < NN) {
        float v = acc[nt][r];
        size_t o = (size_t)row * NH + col;
        if (mode == 0) {
          v += bias[col];
          v = v > 0.f ? v : 0.f;
          unsigned short b = f2bf(v);
          support[(size_t)row * NF + NH + col] = b;
          h32[o] = v;
          h16[o] = b;
        } else if (mode == 1) {
          float hi = bf2f(support[(size_t)row * NF + col]);
          float h0 = bf2f(support[(size_t)row * NF + NH + col]);
          float hp = h32[o];
          float z = theta * v + (1.f - theta) * (0.9f * hi + 0.1f * h0) + hp;
          z = z > 0.f ? z : 0.f;
          h32[o] = z;
          h16[o] = f2bf(z);
        } else {
          float t = v + bias[col];
          t = t > 0.f ? t : 0.f;
          t += axd * bf2f(h16[o]);  // h16 holds h0 during dyn phase
          d32[o] = t;
          d16[o] = f2bf(t);
        }
      }
    }
  }
}

// ---------------- LayerNorm(h)+LayerNorm(d) -> cross_out ----------------
__global__ __launch_bounds__(256)
void ln_cross(const float* __restrict__ h32, const float* __restrict__ d32,
              const float* __restrict__ g1, const float* __restrict__ b1,
              const float* __restrict__ g2, const float* __restrict__ b2,
              float* __restrict__ out1) {
  int lane = threadIdx.x & 63;
  int row = blockIdx.x * 4 + (threadIdx.x >> 6);  // NN/4 blocks exact
  const float* hr = h32 + (size_t)row * NH;
  const float* dr = d32 + (size_t)row * NH;
  float4 hv = *(const float4*)(hr + lane * 4);
  float4 dv = *(const float4*)(dr + lane * 4);
  float sh = hv.x + hv.y + hv.z + hv.w;
  float sd = dv.x + dv.y + dv.z + dv.w;
#pragma unroll
  for (int o = 32; o > 0; o >>= 1) { sh += __shfl_xor(sh, o); sd += __shfl_xor(sd, o); }
  float mh = sh * (1.f / NH), md = sd * (1.f / NH);
  float hcx = hv.x - mh, hcy = hv.y - mh, hcz = hv.z - mh, hcw = hv.w - mh;
  float dcx = dv.x - md, dcy = dv.y - md, dcz = dv.z - md, dcw = dv.w - md;
  float qh = hcx * hcx + hcy * hcy + hcz * hcz + hcw * hcw;
  float qd = dcx * dcx + dcy * dcy + dcz * dcz + dcw * dcw;
#pragma unroll
  for (int o = 32; o > 0; o >>= 1) { qh += __shfl_xor(qh, o); qd += __shfl_xor(qd, o); }
  float ih = rsqrtf(qh * (1.f / NH) + 1e-6f);
  float id = rsqrtf(qd * (1.f / NH) + 1e-6f);
  int c = lane * 4;
  float4 o4;
  o4.x = g1[c + 0] * hcx * ih + b1[c + 0] + g2[c + 0] * dcx * id + b2[c + 0];
  o4.y = g1[c + 1] * hcy * ih + b1[c + 1] + g2[c + 1] * dcy * id + b2[c + 1];
  o4.z = g1[c + 2] * hcz * ih + b1[c + 2] + g2[c + 2] * dcz * id + b2[c + 2];
  o4.w = g1[c + 3] * hcw * ih + b1[c + 3] + g2[c + 3] * dcw * id + b2[c + 3];
  *(float4*)(out1 + (size_t)row * NH + c) = o4;
}

// ---------------- head GEMM (K=256,N=40) + log_softmax ----------------
__global__ __launch_bounds__(256)
void out_head(const float* __restrict__ cross, const float* __restrict__ Wo,
              const float* __restrict__ bo, float* __restrict__ out0) {
  __shared__ float Wl[NH * NC];
  __shared__ float bl[NC];
  for (int i = threadIdx.x; i < NH * NC; i += 256) Wl[i] = Wo[i];
  if (threadIdx.x < NC) bl[threadIdx.x] = bo[threadIdx.x];
  __syncthreads();
  int row = blockIdx.x * 256 + threadIdx.x;
  if (row >= NN) return;
  float acc[NC];
#pragma unroll
  for (int c = 0; c < NC; c++) acc[c] = bl[c];
  const float* xr = cross + (size_t)row * NH;
  for (int k = 0; k < NH; k += 4) {
    float4 xv = *(const float4*)(xr + k);
#pragma unroll
    for (int c = 0; c < NC; c++) {
      acc[c] += xv.x * Wl[(k + 0) * NC + c];
      acc[c] += xv.y * Wl[(k + 1) * NC + c];
      acc[c] += xv.z * Wl[(k + 2) * NC + c];
      acc[c] += xv.w * Wl[(k + 3) * NC + c];
    }
  }
  float m = -1e30f;
#pragma unroll
  for (int c = 0; c < NC; c++) m = fmaxf(m, acc[c]);
  float s = 0.f;
#pragma unroll
  for (int c = 0; c < NC; c++) s += expf(acc[c] - m);
  float ls = m + logf(s);
  float* orow = out0 + (size_t)row * NC;
#pragma unroll
  for (int c = 0; c < NC; c++) orow[c] = acc[c] - ls;
}

// ---------------- launch ----------------
extern "C" void kernel_launch(void* const* d_in, const int* in_sizes, int n_in,
                              void* d_out, int out_size, void* d_ws, size_t ws_size,
                              hipStream_t stream) {
  const float* x    = (const float*)d_in[0];
  const int*   esrc = (const int*)d_in[1];
  const int*   edst = (const int*)d_in[2];
  const float* ew   = (const float*)d_in[3];
  const float* Wfc  = (const float*)d_in[4];
  const float* bfc  = (const float*)d_in[5];
  const float* cvw  = (const float*)d_in[6];
  const float* dyw  = (const float*)d_in[7];
  const float* dyb  = (const float*)d_in[8];
  const float* g1   = (const float*)d_in[9];
  const float* b1   = (const float*)d_in[10];
  const float* g2   = (const float*)d_in[11];
  const float* b2   = (const float*)d_in[12];
  const float* Wout = (const float*)d_in[13];
  const float* bout = (const float*)d_in[14];

  float* out0 = (float*)d_out;                    // [NN,40] log_softmax
  float* out1 = out0 + (size_t)NN * NC;           // [NN,256] cross_out

  char* base = (char*)d_ws;
  size_t off = 0;
  auto carve = [&](size_t bytes) -> void* {
    void* r = base + off;
    off += (bytes + 255) & ~(size_t)255;
    return r;
  };
  unsigned short* support = (unsigned short*)carve((size_t)NN * NF * 2);  // [hi | h0] bf16
  float*          h32     = (float*)carve((size_t)NN * NH * 4);
  unsigned short* h16     = (unsigned short*)carve((size_t)NN * NH * 2);
  float*          d32     = (float*)carve((size_t)NN * NH * 4);
  unsigned short* d16     = (unsigned short*)carve((size_t)NN * NH * 2);
  unsigned short* WfcP    = (unsigned short*)carve((size_t)NF * NH * 2);
  unsigned short* WcvP    = (unsigned short*)carve((size_t)NL * NF * NH * 2);
  unsigned short* WdyP    = (unsigned short*)carve((size_t)NL * NH * NH * 2);
  int*   rp  = (int*)carve((size_t)(NN + 1) * 4);
  int*   nxt = (int*)carve((size_t)NN * 4);
  int*   cs  = (int*)carve((size_t)NE * 4);
  float* cw  = (float*)carve((size_t)NE * 4);

  const int GEMM_GRID = (NN + 63) / 64;  // 1563

  // weights
  pack_w<<<(NF * NH) / 256, 256, 0, stream>>>(Wfc, WfcP, NF);
  for (int l = 0; l < NL; l++)
    pack_w<<<(NF * NH) / 256, 256, 0, stream>>>(cvw + (size_t)l * NF * NH,
                                                WcvP + (size_t)l * (NF / 32) * NH * 32, NF);
  pack_dyn<<<(NL * NH * NH) / 256, 256, 0, stream>>>(dyw, WdyP);

  // CSR
  hipMemsetAsync(nxt, 0, (size_t)NN * 4, stream);
  count_deg<<<NE / 256, 256, 0, stream>>>(edst, nxt);
  scan_deg<<<1, 256, 0, stream>>>(nxt, rp);
  scatter_edges<<<NE / 256, 256, 0, stream>>>(esrc, edst, ew, nxt, cs, cw);

  // fc: h0 = relu(x @ Wfc + bfc)
  gemm256<true><<<GEMM_GRID, 256, 0, stream>>>(x, NF, NF, WfcP, 0, 0.f, bfc,
                                               support, h32, h16, d32, d16, 0.f);

  // dynamic branch (before conv so h16 still holds h0)
  for (int l = 0; l < NL; l++) {
    const void* A = (l == 0) ? (const void*)h16 : (const void*)d16;
    gemm256<false><<<GEMM_GRID, 256, 0, stream>>>(A, NH, NH,
        WdyP + (size_t)l * (NH / 32) * NH * 32, 2, 0.f, dyb + (size_t)l * NH,
        support, h32, h16, d32, d16, (l == 0) ? 0.f : 0.1f);
  }

  // conv stack
  for (int l = 0; l < NL; l++) {
    spmm_kernel<<<NN, 128, 0, stream>>>(rp, cs, cw, h16, support);
    float theta = logf(0.5f / (float)(l + 1) + 1.0f);
    gemm256<false><<<GEMM_GRID, 256, 0, stream>>>(support, NF, NF,
        WcvP + (size_t)l * (NF / 32) * NH * 32, 1, theta, nullptr,
        support, h32, h16, d32, d16, 0.f);
  }

  ln_cross<<<NN / 4, 256, 0, stream>>>(h32, d32, g1, b1, g2, b2, out1);
  out_head<<<(NN + 255) / 256, 256, 0, stream>>>(out1, Wout, bout, out0);
}

// Round 3
// 5254.171 us; speedup vs baseline: 1.6764x; 1.6764x over previous
//
#include <hip/hip_runtime.h>
#include <math.h>
#include <stdint.h>

#define NN 100000   // nodes
#define NE 3200000  // edges
#define NF 512      // feat
#define NH 256      // hidden
#define NC 40       // classes
#define NL 8        // layers

typedef __attribute__((ext_vector_type(8))) short short8;
typedef __attribute__((ext_vector_type(4))) float f32x4;

__device__ __forceinline__ unsigned short f2bf(float f) {
  union { float f; unsigned u; } v; v.f = f;
  return (unsigned short)((v.u + 0x7fffu + ((v.u >> 16) & 1u)) >> 16);
}
__device__ __forceinline__ float bf2f(unsigned short h) {
  union { unsigned u; float f; } v; v.u = ((unsigned)h) << 16;
  return v.f;
}
__device__ __forceinline__ float bflo(unsigned u) {
  union { unsigned v; float f; } x; x.v = u << 16; return x.f;
}
__device__ __forceinline__ float bfhi(unsigned u) {
  union { unsigned v; float f; } x; x.v = u & 0xffff0000u; return x.f;
}

#define GL2LDS(gp, lp) __builtin_amdgcn_global_load_lds( \
    (const __attribute__((address_space(1))) unsigned int*)(gp), \
    (__attribute__((address_space(3))) unsigned int*)(lp), 16, 0, 0)

// ---------------- weight packing: W[K,256] f32 -> bf16 packed [K/32][256][32] ----------------
__global__ void pack_w(const float* __restrict__ W, unsigned short* __restrict__ out, int K) {
  int idx = blockIdx.x * 256 + threadIdx.x;  // grid covers K*256 exactly
  int k = idx >> 8, n = idx & 255;
  out[((size_t)(k >> 5) * NH + n) * 32 + (k & 31)] = f2bf(W[(size_t)k * NH + n]);
}

// dyn fold: Wd[l][k][n] = dyn_w[l][k][n] - dyn_w[l][k+256][n], packed per layer
__global__ void pack_dyn(const float* __restrict__ dynw, unsigned short* __restrict__ out) {
  int idx = blockIdx.x * 256 + threadIdx.x;  // NL*256*256
  int l = idx >> 16;
  int r = idx & 65535;
  int k = r >> 8, n = r & 255;
  float v = dynw[(size_t)l * NF * NH + (size_t)k * NH + n] -
            dynw[(size_t)l * NF * NH + (size_t)(k + NH) * NH + n];
  out[(size_t)l * 65536 + ((size_t)(k >> 5) * NH + n) * 32 + (k & 31)] = f2bf(v);
}

// ---------------- CSR build ----------------
__global__ void count_deg(const int* __restrict__ dst, int* __restrict__ deg) {
  int i = blockIdx.x * 256 + threadIdx.x;  // NE exact
  atomicAdd(&deg[dst[i]], 1);
}

__global__ void scan_deg(int* __restrict__ deg, int* __restrict__ rp) {
  __shared__ int sums[256];
  int t = threadIdx.x;
  const int CH = (NN + 255) / 256;  // 391
  int lo = t * CH, hi = lo + CH; if (hi > NN) hi = NN;
  int s = 0;
  for (int i = lo; i < hi; i++) s += deg[i];
  sums[t] = s; __syncthreads();
  for (int off = 1; off < 256; off <<= 1) {
    int v = (t >= off) ? sums[t - off] : 0;
    __syncthreads();
    sums[t] += v;
    __syncthreads();
  }
  int run = (t == 0) ? 0 : sums[t - 1];
  for (int i = lo; i < hi; i++) {
    int dv = deg[i];          // read before overwrite (deg aliases 'next')
    rp[i] = run; deg[i] = run;
    run += dv;
  }
  if (t == 255) rp[NN] = run;
}

__global__ void scatter_edges(const int* __restrict__ src, const int* __restrict__ dst,
                              const float* __restrict__ w, int* __restrict__ nxt,
                              int* __restrict__ cs, float* __restrict__ cw) {
  int i = blockIdx.x * 256 + threadIdx.x;  // NE exact
  int d = dst[i];
  int p = atomicAdd(&nxt[d], 1);
  cs[p] = src[i];
  cw[p] = w[i];
}

// ---------------- SpMM v2: support[:, :256] = bf16( adj @ h_bf16 ) ----------------
// 4 waves/block, one node per wave; lane handles 4 feats (8B gather per edge), edges unrolled x2.
__global__ __launch_bounds__(256)
void spmm_v2(const int* __restrict__ rp, const int* __restrict__ cs,
             const float* __restrict__ cw,
             const unsigned short* __restrict__ h16,
             unsigned short* __restrict__ support) {
  int wave = threadIdx.x >> 6, lane = threadIdx.x & 63;
  int node = blockIdx.x * 4 + wave;  // grid = NN/4 = 25000 exact
  int f = lane * 4;
  const unsigned short* hb = h16 + f;
  int beg = rp[node], end = rp[node + 1];
  float a0 = 0.f, a1 = 0.f, a2 = 0.f, a3 = 0.f;
  int e = beg;
  for (; e + 2 <= end; e += 2) {
    int s0 = cs[e], s1 = cs[e + 1];
    float w0 = cw[e], w1 = cw[e + 1];
    uint2 p0 = *(const uint2*)(hb + (size_t)s0 * NH);
    uint2 p1 = *(const uint2*)(hb + (size_t)s1 * NH);
    a0 += w0 * bflo(p0.x); a1 += w0 * bfhi(p0.x);
    a2 += w0 * bflo(p0.y); a3 += w0 * bfhi(p0.y);
    a0 += w1 * bflo(p1.x); a1 += w1 * bfhi(p1.x);
    a2 += w1 * bflo(p1.y); a3 += w1 * bfhi(p1.y);
  }
  if (e < end) {
    int s0 = cs[e]; float w0 = cw[e];
    uint2 p0 = *(const uint2*)(hb + (size_t)s0 * NH);
    a0 += w0 * bflo(p0.x); a1 += w0 * bfhi(p0.x);
    a2 += w0 * bflo(p0.y); a3 += w0 * bfhi(p0.y);
  }
  uint2 o;
  o.x = (unsigned)f2bf(a0) | ((unsigned)f2bf(a1) << 16);
  o.y = (unsigned)f2bf(a2) | ((unsigned)f2bf(a3) << 16);
  *(uint2*)(support + (size_t)node * NF + f) = o;
}

// ---------------- MFMA GEMM, m97 structure: 128x128 tile, global_load_lds staging ----------------
// C[M,256] = A[M,K] @ Bpack, fused epilogues:
// mode 0 = FC:   v = relu(acc + bias);       write support[:,256:], h32, h16
// mode 1 = CONV: z = relu(theta*acc + (1-theta)*(0.9*hi + 0.1*h0) + h_prev); write h32, h16
// mode 2 = DYN:  t = relu(acc + bias) + axd * h0;  write d16 XOR d32 (wd32 selects)
// NOTE: dyn chain MUST NOT write the buffer it reads (blockIdx.y splits N — other
// blocks read all K cols of the same rows). Launcher ping-pongs d buffers.
template <bool AF32>
__global__ __launch_bounds__(256)
void gemm_tile(const void* __restrict__ Aptr, int lda, int K,
               const unsigned short* __restrict__ Bp,
               int mode, float theta, const float* __restrict__ bias,
               unsigned short* __restrict__ support,
               float* __restrict__ h32, unsigned short* __restrict__ h16,
               float* __restrict__ d32, unsigned short* __restrict__ d16,
               float axd, int wd32) {
  constexpr int ABYTES = AF32 ? 16384 : 8192;   // A tile 128 x 32 elems
  constexpr int NAJ = AF32 ? 4 : 2;             // staging issues per thread for A
  __shared__ char smem[ABYTES + 8192];          // + B tile 32k x 128n bf16

  const int tid = threadIdx.x;
  const int wave = tid >> 6, lane = tid & 63;
  const int quad = lane >> 4, lrow = lane & 15;
  const int wm = wave >> 1, wn = wave & 1;
  const int bm = blockIdx.x * 128;
  const int cn = blockIdx.y * 128;

  // A staging source pointers: LDS layout row-major [128][32 elems], lane-contiguous
  const char* Ag[NAJ];
#pragma unroll
  for (int j = 0; j < NAJ; j++) {
    int row, chunk;
    if (AF32) { row = (tid >> 3) + j * 32; chunk = tid & 7; }
    else      { row = (tid >> 2) + j * 64; chunk = tid & 3; }
    int gr = bm + row; if (gr > NN - 1) gr = NN - 1;
    Ag[j] = (const char*)Aptr + (size_t)gr * lda * (AF32 ? 4 : 2) + (size_t)chunk * 16;
  }
  // B staging: per k-step the [128 col][32 k] slice is 8KB contiguous in Bpack
  const char* Bg = (const char*)Bp + (size_t)cn * 64 + (size_t)tid * 16;

  f32x4 acc[4][4];
  f32x4 zero = {0.f, 0.f, 0.f, 0.f};
#pragma unroll
  for (int i = 0; i < 4; i++)
#pragma unroll
    for (int j = 0; j < 4; j++) acc[i][j] = zero;

  const int KS = K >> 5;
  for (int ks = 0; ks < KS; ks++) {
    // stage A
#pragma unroll
    for (int j = 0; j < NAJ; j++)
      GL2LDS(Ag[j] + (size_t)ks * (AF32 ? 128 : 64), smem + tid * 16 + j * 4096);
    // stage B (2 issues)
#pragma unroll
    for (int j = 0; j < 2; j++)
      GL2LDS(Bg + (size_t)ks * 16384 + j * 4096, smem + ABYTES + tid * 16 + j * 4096);
    __syncthreads();

    short8 af[4], bfr[4];
    const unsigned short* lB = (const unsigned short*)(smem + ABYTES);
#pragma unroll
    for (int nt = 0; nt < 4; nt++)
      bfr[nt] = *(const short8*)(lB + (size_t)(wn * 64 + nt * 16 + lrow) * 32 + quad * 8);
    if (AF32) {
      const float* lA = (const float*)smem;
#pragma unroll
      for (int mt = 0; mt < 4; mt++) {
        const float* p = lA + (size_t)(wm * 64 + mt * 16 + lrow) * 32 + quad * 8;
        float4 x0 = *(const float4*)p;
        float4 x1 = *(const float4*)(p + 4);
        short8 a;
        a[0] = (short)f2bf(x0.x); a[1] = (short)f2bf(x0.y);
        a[2] = (short)f2bf(x0.z); a[3] = (short)f2bf(x0.w);
        a[4] = (short)f2bf(x1.x); a[5] = (short)f2bf(x1.y);
        a[6] = (short)f2bf(x1.z); a[7] = (short)f2bf(x1.w);
        af[mt] = a;
      }
    } else {
      const unsigned short* lA = (const unsigned short*)smem;
#pragma unroll
      for (int mt = 0; mt < 4; mt++)
        af[mt] = *(const short8*)(lA + (size_t)(wm * 64 + mt * 16 + lrow) * 32 + quad * 8);
    }
#pragma unroll
    for (int mt = 0; mt < 4; mt++)
#pragma unroll
      for (int nt = 0; nt < 4; nt++)
        acc[mt][nt] = __builtin_amdgcn_mfma_f32_16x16x32_bf16(af[mt], bfr[nt], acc[mt][nt], 0, 0, 0);
    __syncthreads();
  }

  // epilogue
#pragma unroll
  for (int mt = 0; mt < 4; mt++) {
#pragma unroll
    for (int nt = 0; nt < 4; nt++) {
      int col = cn + wn * 64 + nt * 16 + lrow;
#pragma unroll
      for (int r = 0; r < 4; r++) {
        int row = bm + wm * 64 + mt * 16 + quad * 4 + r;
        if (row < NN) {
          float v = acc[mt][nt][r];
          size_t o = (size_t)row * NH + col;
          if (mode == 0) {
            v += bias[col];
            v = v > 0.f ? v : 0.f;
            unsigned short b = f2bf(v);
            support[(size_t)row * NF + NH + col] = b;
            h32[o] = v;
            h16[o] = b;
          } else if (mode == 1) {
            float hi = bf2f(support[(size_t)row * NF + col]);
            float h0 = bf2f(support[(size_t)row * NF + NH + col]);
            float hp = h32[o];
            float z = theta * v + (1.f - theta) * (0.9f * hi + 0.1f * h0) + hp;
            z = z > 0.f ? z : 0.f;
            h32[o] = z;
            h16[o] = f2bf(z);
          } else {
            float t = v + bias[col];
            t = t > 0.f ? t : 0.f;
            t += axd * bf2f(h16[o]);  // h16 holds h0 during dyn phase
            if (wd32) d32[o] = t;     // final layer: f32 only (d16 never read again)
            else      d16[o] = f2bf(t);
          }
        }
      }
    }
  }
}

// ---------------- LayerNorm(h)+LayerNorm(d) -> cross_out ----------------
__global__ __launch_bounds__(256)
void ln_cross(const float* __restrict__ h32, const float* __restrict__ d32,
              const float* __restrict__ g1, const float* __restrict__ b1,
              const float* __restrict__ g2, const float* __restrict__ b2,
              float* __restrict__ out1) {
  int lane = threadIdx.x & 63;
  int row = blockIdx.x * 4 + (threadIdx.x >> 6);  // NN/4 blocks exact
  const float* hr = h32 + (size_t)row * NH;
  const float* dr = d32 + (size_t)row * NH;
  float4 hv = *(const float4*)(hr + lane * 4);
  float4 dv = *(const float4*)(dr + lane * 4);
  float sh = hv.x + hv.y + hv.z + hv.w;
  float sd = dv.x + dv.y + dv.z + dv.w;
#pragma unroll
  for (int o = 32; o > 0; o >>= 1) { sh += __shfl_xor(sh, o); sd += __shfl_xor(sd, o); }
  float mh = sh * (1.f / NH), md = sd * (1.f / NH);
  float hcx = hv.x - mh, hcy = hv.y - mh, hcz = hv.z - mh, hcw = hv.w - mh;
  float dcx = dv.x - md, dcy = dv.y - md, dcz = dv.z - md, dcw = dv.w - md;
  float qh = hcx * hcx + hcy * hcy + hcz * hcz + hcw * hcw;
  float qd = dcx * dcx + dcy * dcy + dcz * dcz + dcw * dcw;
#pragma unroll
  for (int o = 32; o > 0; o >>= 1) { qh += __shfl_xor(qh, o); qd += __shfl_xor(qd, o); }
  float ih = rsqrtf(qh * (1.f / NH) + 1e-6f);
  float id = rsqrtf(qd * (1.f / NH) + 1e-6f);
  int c = lane * 4;
  float4 o4;
  o4.x = g1[c + 0] * hcx * ih + b1[c + 0] + g2[c + 0] * dcx * id + b2[c + 0];
  o4.y = g1[c + 1] * hcy * ih + b1[c + 1] + g2[c + 1] * dcy * id + b2[c + 1];
  o4.z = g1[c + 2] * hcz * ih + b1[c + 2] + g2[c + 2] * dcz * id + b2[c + 2];
  o4.w = g1[c + 3] * hcw * ih + b1[c + 3] + g2[c + 3] * dcw * id + b2[c + 3];
  *(float4*)(out1 + (size_t)row * NH + c) = o4;
}

// ---------------- head GEMM (K=256,N=40) + log_softmax ----------------
__global__ __launch_bounds__(256)
void out_head(const float* __restrict__ cross, const float* __restrict__ Wo,
              const float* __restrict__ bo, float* __restrict__ out0) {
  __shared__ float Wl[NH * NC];
  __shared__ float bl[NC];
  for (int i = threadIdx.x; i < NH * NC; i += 256) Wl[i] = Wo[i];
  if (threadIdx.x < NC) bl[threadIdx.x] = bo[threadIdx.x];
  __syncthreads();
  int row = blockIdx.x * 256 + threadIdx.x;
  if (row >= NN) return;
  float acc[NC];
#pragma unroll
  for (int c = 0; c < NC; c++) acc[c] = bl[c];
  const float* xr = cross + (size_t)row * NH;
  for (int k = 0; k < NH; k += 4) {
    float4 xv = *(const float4*)(xr + k);
#pragma unroll
    for (int c = 0; c < NC; c++) {
      acc[c] += xv.x * Wl[(k + 0) * NC + c];
      acc[c] += xv.y * Wl[(k + 1) * NC + c];
      acc[c] += xv.z * Wl[(k + 2) * NC + c];
      acc[c] += xv.w * Wl[(k + 3) * NC + c];
    }
  }
  float m = -1e30f;
#pragma unroll
  for (int c = 0; c < NC; c++) m = fmaxf(m, acc[c]);
  float s = 0.f;
#pragma unroll
  for (int c = 0; c < NC; c++) s += expf(acc[c] - m);
  float ls = m + logf(s);
  float* orow = out0 + (size_t)row * NC;
#pragma unroll
  for (int c = 0; c < NC; c++) orow[c] = acc[c] - ls;
}

// ---------------- launch ----------------
extern "C" void kernel_launch(void* const* d_in, const int* in_sizes, int n_in,
                              void* d_out, int out_size, void* d_ws, size_t ws_size,
                              hipStream_t stream) {
  const float* x    = (const float*)d_in[0];
  const int*   esrc = (const int*)d_in[1];
  const int*   edst = (const int*)d_in[2];
  const float* ew   = (const float*)d_in[3];
  const float* Wfc  = (const float*)d_in[4];
  const float* bfc  = (const float*)d_in[5];
  const float* cvw  = (const float*)d_in[6];
  const float* dyw  = (const float*)d_in[7];
  const float* dyb  = (const float*)d_in[8];
  const float* g1   = (const float*)d_in[9];
  const float* b1   = (const float*)d_in[10];
  const float* g2   = (const float*)d_in[11];
  const float* b2   = (const float*)d_in[12];
  const float* Wout = (const float*)d_in[13];
  const float* bout = (const float*)d_in[14];

  float* out0 = (float*)d_out;                    // [NN,40] log_softmax
  float* out1 = out0 + (size_t)NN * NC;           // [NN,256] cross_out

  char* base = (char*)d_ws;
  size_t off = 0;
  auto carve = [&](size_t bytes) -> void* {
    void* r = base + off;
    off += (bytes + 255) & ~(size_t)255;
    return r;
  };
  unsigned short* support = (unsigned short*)carve((size_t)NN * NF * 2);  // [hi | h0] bf16
  float*          h32     = (float*)carve((size_t)NN * NH * 4);
  unsigned short* h16     = (unsigned short*)carve((size_t)NN * NH * 2);
  float*          d32     = (float*)carve((size_t)NN * NH * 4);
  unsigned short* d16     = (unsigned short*)carve((size_t)NN * NH * 2);
  unsigned short* WfcP    = (unsigned short*)carve((size_t)NF * NH * 2);
  unsigned short* WcvP    = (unsigned short*)carve((size_t)NL * NF * NH * 2);
  unsigned short* WdyP    = (unsigned short*)carve((size_t)NL * NH * NH * 2);
  int*   rp  = (int*)carve((size_t)(NN + 1) * 4);
  int*   nxt = (int*)carve((size_t)NN * 4);
  int*   cs  = (int*)carve((size_t)NE * 4);
  float* cw  = (float*)carve((size_t)NE * 4);

  // dyn ping-pong buffers: even-layer outputs -> d16 (dedicated);
  // odd-layer outputs (l=1,3,5) -> scratch aliased on d32 (d32 is dead until l=7,
  // and l=7 writes ONLY d32 f32, reading from d16). No buffer is read+written
  // in the same dispatch.
  unsigned short* dA = d16;
  unsigned short* dB = (unsigned short*)d32;

  const dim3 GG((NN + 127) / 128, 2);  // 782 x 2

  // weights
  pack_w<<<(NF * NH) / 256, 256, 0, stream>>>(Wfc, WfcP, NF);
  for (int l = 0; l < NL; l++)
    pack_w<<<(NF * NH) / 256, 256, 0, stream>>>(cvw + (size_t)l * NF * NH,
                                                WcvP + (size_t)l * (NF / 32) * NH * 32, NF);
  pack_dyn<<<(NL * NH * NH) / 256, 256, 0, stream>>>(dyw, WdyP);

  // CSR
  hipMemsetAsync(nxt, 0, (size_t)NN * 4, stream);
  count_deg<<<NE / 256, 256, 0, stream>>>(edst, nxt);
  scan_deg<<<1, 256, 0, stream>>>(nxt, rp);
  scatter_edges<<<NE / 256, 256, 0, stream>>>(esrc, edst, ew, nxt, cs, cw);

  // fc: h0 = relu(x @ Wfc + bfc)
  gemm_tile<true><<<GG, 256, 0, stream>>>(x, NF, NF, WfcP, 0, 0.f, bfc,
                                          support, h32, h16, d32, d16, 0.f, 0);

  // dynamic branch (before conv so h16 still holds h0)
  for (int l = 0; l < NL; l++) {
    const void* A = (l == 0) ? (const void*)h16
                             : (const void*)((l & 1) ? dA : dB);  // output of layer l-1
    unsigned short* dOut = (l & 1) ? dB : dA;
    int wd32 = (l == NL - 1) ? 1 : 0;
    gemm_tile<false><<<GG, 256, 0, stream>>>(A, NH, NH,
        WdyP + (size_t)l * (NH / 32) * NH * 32, 2, 0.f, dyb + (size_t)l * NH,
        support, h32, h16, d32, dOut, (l == 0) ? 0.f : 0.1f, wd32);
  }

  // conv stack
  for (int l = 0; l < NL; l++) {
    spmm_v2<<<NN / 4, 256, 0, stream>>>(rp, cs, cw, h16, support);
    float theta = logf(0.5f / (float)(l + 1) + 1.0f);
    gemm_tile<false><<<GG, 256, 0, stream>>>(support, NF, NF,
        WcvP + (size_t)l * (NF / 32) * NH * 32, 1, theta, nullptr,
        support, h32, h16, d32, d16, 0.f, 0);
  }

  ln_cross<<<NN / 4, 256, 0, stream>>>(h32, d32, g1, b1, g2, b2, out1);
  out_head<<<(NN + 255) / 256, 256, 0, stream>>>(out1, Wout, bout, out0);
}